// Round 2
// baseline (927.394 us; speedup 1.0000x reference)
//
#include <hip/hip_runtime.h>
#include <hip/hip_bf16.h>
#include <cmath>

typedef __hip_bfloat16 bf16;
typedef __bf16 bf16x8 __attribute__((ext_vector_type(8)));
typedef float f32x4 __attribute__((ext_vector_type(4)));

typedef __attribute__((address_space(1))) void void_g;
typedef __attribute__((address_space(3))) void void_l;

#define SEQ 2048
#define DMODEL 1024
#define NHEAD 16
#define HDIM 64
#define DFF 4096
#define WINDOW 128
#define LN_EPS 1e-5f

__device__ __forceinline__ void gl_lds16(const bf16* g, bf16* l) {
    __builtin_amdgcn_global_load_lds((void_g*)(g), (void_l*)(l), 16, 0, 0);
}

__device__ __forceinline__ bf16x8 cvt8(float4 a, float4 b) {
    bf16x8 w;
    w[0] = (__bf16)a.x; w[1] = (__bf16)a.y; w[2] = (__bf16)a.z; w[3] = (__bf16)a.w;
    w[4] = (__bf16)b.x; w[5] = (__bf16)b.y; w[6] = (__bf16)b.z; w[7] = (__bf16)b.w;
    return w;
}

// ---------------- zero f32 buffer ----------------
__global__ __launch_bounds__(256)
void zero_f32(float4* __restrict__ p) {
    p[blockIdx.x * 256 + threadIdx.x] = (float4){0.f, 0.f, 0.f, 0.f};
}

// ---------------- positional encoding add: f32 in -> bf16 out ----------------
__global__ __launch_bounds__(256)
void add_pe(const float* __restrict__ X, bf16* __restrict__ x) {
    int idx = blockIdx.x * 256 + threadIdx.x;
    int s = idx >> 10, d = idx & 1023;
    float i2 = (float)(d & ~1);
    float div = expf(i2 * (-9.210340371976184f / 1024.0f));
    float ang = (float)s * div;
    float pe = (d & 1) ? cosf(ang) : sinf(ang);
    x[idx] = (bf16)(X[idx] + pe);
}

// ======================= GEMM core, BK=64, double-buffered LDS =======================
// Single barrier per K-step: stage tile t+1 (W via reg-cvt ds_write, A via
// global_load_lds) BEFORE computing tile t; __syncthreads at the end of the
// iteration both publishes the ds_writes and (via the compiler's vmcnt(0)
// drain) completes the async A loads -- their latency overlaps the MFMA phase.
// LDS layout per buffer: two ks-major halves of 128x32 bf16 (proven swizzle).
// chunk c in [0,1024): ks=c>>9, row=(c>>2)&127, kch=(c&3)^(row&3)
// frag read (half ks): elems ks*4096 + row*32 + (quad^(r&3))*8

#define GEMM_PROLOGUE(Adecl, Wdecl)                                              \
    __shared__ __align__(16) bf16 Asbuf[2][128 * 64];                            \
    __shared__ __align__(16) bf16 Wsbuf[2][128 * 64];                            \
    bf16* const As0 = Asbuf[0]; bf16* const As1 = Asbuf[1];                      \
    bf16* const Ws0 = Wsbuf[0]; bf16* const Ws1 = Wsbuf[1];                      \
    const int tid  = threadIdx.x;                                                \
    const int lane = tid & 63;                                                   \
    const int wave = tid >> 6;                                                   \
    const int wr = wave >> 1, wc = wave & 1;                                     \
    const int r = lane & 15, quad = lane >> 4;                                   \
    const int rc = (quad ^ (r & 3)) * 8;                                         \
    f32x4 acc[4][4];                                                             \
    _Pragma("unroll")                                                            \
    for (int i = 0; i < 4; ++i)                                                  \
        _Pragma("unroll")                                                        \
        for (int j = 0; j < 4; ++j) acc[i][j] = (f32x4){0.f, 0.f, 0.f, 0.f};     \
    const bf16* Ap[4]; const float* Wp[4];                                       \
    _Pragma("unroll")                                                            \
    for (int i = 0; i < 4; ++i) {                                                \
        int c = tid + 256 * i;                                                   \
        int ks = c >> 9, row = (c >> 2) & 127, kch = (c & 3) ^ (row & 3);        \
        Ap[i] = (Adecl) + (size_t)(m0 + row) * K + ks * 32 + kch * 8;            \
        Wp[i] = (Wdecl) + (size_t)(n0 + row) * K + ks * 32 + kch * 8;            \
    }

#define GEMM_KLOOP(Klim)                                                         \
    const int nit = (Klim) / 64;                                                 \
    float4 w0[4], w1[4];                                                         \
    _Pragma("unroll")                                                            \
    for (int i = 0; i < 4; ++i) {                                                \
        w0[i] = *(const float4*)(Wp[i]);                                         \
        w1[i] = *(const float4*)(Wp[i] + 4);                                     \
    }                                                                            \
    _Pragma("unroll")                                                            \
    for (int i = 0; i < 4; ++i) {                                                \
        *(bf16x8*)(Ws0 + (size_t)(tid + 256 * i) * 8) = cvt8(w0[i], w1[i]);      \
        gl_lds16(Ap[i], As0 + (size_t)(tid + 256 * i) * 8);                      \
    }                                                                            \
    if (nit > 1) {                                                               \
        _Pragma("unroll")                                                        \
        for (int i = 0; i < 4; ++i) {                                            \
            w0[i] = *(const float4*)(Wp[i] + 64);                                \
            w1[i] = *(const float4*)(Wp[i] + 68);                                \
        }                                                                        \
    }                                                                            \
    __syncthreads();                                                             \
    for (int t = 0; t < nit; ++t) {                                              \
        bf16* const Asc = (t & 1) ? As1 : As0;                                   \
        bf16* const Wsc = (t & 1) ? Ws1 : Ws0;                                   \
        if (t + 1 < nit) {                                                       \
            bf16* const Asn = (t & 1) ? As0 : As1;                               \
            bf16* const Wsn = (t & 1) ? Ws0 : Ws1;                               \
            _Pragma("unroll")                                                    \
            for (int i = 0; i < 4; ++i) {                                        \
                *(bf16x8*)(Wsn + (size_t)(tid + 256 * i) * 8) = cvt8(w0[i], w1[i]); \
                gl_lds16(Ap[i] + (t + 1) * 64, Asn + (size_t)(tid + 256 * i) * 8);  \
            }                                                                    \
            if (t + 2 < nit) {                                                   \
                _Pragma("unroll")                                                \
                for (int i = 0; i < 4; ++i) {                                    \
                    w0[i] = *(const float4*)(Wp[i] + (t + 2) * 64);              \
                    w1[i] = *(const float4*)(Wp[i] + (t + 2) * 64 + 4);          \
                }                                                                \
            }                                                                    \
        }                                                                        \
        _Pragma("unroll")                                                        \
        for (int ks = 0; ks < 2; ++ks) {                                         \
            bf16x8 a[4], b[4];                                                   \
            _Pragma("unroll")                                                    \
            for (int mt = 0; mt < 4; ++mt)                                       \
                a[mt] = *(const bf16x8*)(Asc + ks*4096 + (wr*64+mt*16+r)*32 + rc);\
            _Pragma("unroll")                                                    \
            for (int nt = 0; nt < 4; ++nt)                                       \
                b[nt] = *(const bf16x8*)(Wsc + ks*4096 + (wc*64+nt*16+r)*32 + rc);\
            _Pragma("unroll")                                                    \
            for (int mt = 0; mt < 4; ++mt)                                       \
                _Pragma("unroll")                                                \
                for (int nt = 0; nt < 4; ++nt)                                   \
                    acc[mt][nt] = __builtin_amdgcn_mfma_f32_16x16x32_bf16(       \
                        a[mt], b[nt], acc[mt][nt], 0, 0, 0);                     \
        }                                                                        \
        __syncthreads();                                                         \
    }

// ---------------- direct GEMM: C[M,N] = A[M,K]*W[N,K]^T + bias, f32 W ----------------
template<int ACT>
__global__ __launch_bounds__(256)
void gemm_bt(const bf16* __restrict__ A, const float* __restrict__ W,
             const float* __restrict__ bias, bf16* __restrict__ C,
             int M, int N, int K)
{
    const int m0 = blockIdx.y * 128, n0 = blockIdx.x * 128;
    GEMM_PROLOGUE(A, W)
    GEMM_KLOOP(K)
#pragma unroll
    for (int nt = 0; nt < 4; ++nt) {
        int n = n0 + wc * 64 + nt * 16 + r;
        float bv = bias[n];
#pragma unroll
        for (int mt = 0; mt < 4; ++mt) {
#pragma unroll
            for (int e = 0; e < 4; ++e) {
                int m = m0 + wr * 64 + mt * 16 + quad * 4 + e;
                float v = acc[mt][nt][e] + bv;
                if (ACT == 1) v = fmaxf(v, 0.f);
                C[(size_t)m * N + n] = (bf16)v;
            }
        }
    }
}

// ---------------- split-K GEMM: Cacc += A*W^T (f32 atomic), f32 W ----------------
template<int SPLIT>
__global__ __launch_bounds__(256)
void gemm_bt_splitk(const bf16* __restrict__ A, const float* __restrict__ Wfull,
                    float* __restrict__ Cacc, int M, int N, int K)
{
    const int m0 = blockIdx.y * 128, n0 = blockIdx.x * 128;
    const int Kc = K / SPLIT;
    const bf16* Ab = A + (size_t)blockIdx.z * Kc;
    const float* W = Wfull + (size_t)blockIdx.z * Kc;
    GEMM_PROLOGUE(Ab, W)
    GEMM_KLOOP(Kc)
#pragma unroll
    for (int nt = 0; nt < 4; ++nt) {
        int n = n0 + wc * 64 + nt * 16 + r;
#pragma unroll
        for (int mt = 0; mt < 4; ++mt) {
#pragma unroll
            for (int e = 0; e < 4; ++e) {
                int m = m0 + wr * 64 + mt * 16 + quad * 4 + e;
                atomicAdd(&Cacc[(size_t)m * N + n], acc[mt][nt][e]);
            }
        }
    }
}

// ---------------- V transpose: qkv v-part [s][h*64+d] -> Vt[h*64+d][s] ----------------
__global__ __launch_bounds__(256)
void transpose_v(const bf16* __restrict__ qkv, bf16* __restrict__ Vt)
{
    __shared__ __bf16 t[64][66];
    const int s0 = blockIdx.x * 64, dm0 = blockIdx.y * 64;
    const int tid = threadIdx.x;
    const int sl = tid >> 2, dc = (tid & 3) * 16;
    const bf16* src = qkv + (size_t)(s0 + sl) * 3072 + 2048 + dm0 + dc;
    bf16x8 v0 = *(const bf16x8*)(src);
    bf16x8 v1 = *(const bf16x8*)(src + 8);
#pragma unroll
    for (int j = 0; j < 8; ++j) { t[sl][dc + j] = v0[j]; t[sl][dc + 8 + j] = v1[j]; }
    __syncthreads();
    const int dl = tid >> 2, sc = (tid & 3) * 16;
    bf16x8 o0, o1;
#pragma unroll
    for (int j = 0; j < 8; ++j) { o0[j] = t[sc + j][dl]; o1[j] = t[sc + 8 + j][dl]; }
    bf16* dst = Vt + (size_t)(dm0 + dl) * SEQ + s0 + sc;
    *(bf16x8*)(dst) = o0;
    *(bf16x8*)(dst + 8) = o1;
}

// ---------------- banded flash attention with MFMA ----------------
__global__ __launch_bounds__(256)
void attn_mfma(const bf16* __restrict__ qkv, const bf16* __restrict__ Vt,
               bf16* __restrict__ o)
{
    __shared__ __align__(16) __bf16 Plds[4][16 * 40];
    const int tid = threadIdx.x, lane = tid & 63, w = tid >> 6;
    const int h = blockIdx.x & 15;
    const int qw = (blockIdx.x >> 4) * 64 + w * 16;
    const int r = lane & 15, quad = lane >> 4;
    __bf16* P = Plds[w];

    bf16x8 qa[2];
    {
        const bf16* qrow = qkv + (size_t)(qw + r) * 3072 + h * 64 + quad * 8;
#pragma unroll
        for (int c = 0; c < 2; ++c) {
            bf16x8 t = *(const bf16x8*)(qrow + c * 32);
#pragma unroll
            for (int j = 0; j < 8; ++j) qa[c][j] = (__bf16)((float)t[j] * 0.125f);
        }
    }

    bf16x8 ones;
#pragma unroll
    for (int j = 0; j < 8; ++j) ones[j] = (__bf16)1.0f;

    f32x4 acc[4];
#pragma unroll
    for (int d = 0; d < 4; ++d) acc[d] = (f32x4){0.f, 0.f, 0.f, 0.f};
    float m_run[4], l_run[4];
#pragma unroll
    for (int e = 0; e < 4; ++e) { m_run[e] = -1e30f; l_run[e] = 0.f; }

    int jmin = qw - (WINDOW - 1); if (jmin < 0) jmin = 0;
    int jmax = qw + 15 + (WINDOW - 1); if (jmax > SEQ - 1) jmax = SEQ - 1;

    for (int kt = jmin & ~31; kt <= jmax; kt += 32) {
        f32x4 S[2];
#pragma unroll
        for (int c = 0; c < 2; ++c) {
            const bf16* krow = qkv + (size_t)(kt + 16 * c + r) * 3072 + 1024 + h * 64 + quad * 8;
            bf16x8 kb0 = *(const bf16x8*)(krow);
            bf16x8 kb1 = *(const bf16x8*)(krow + 32);
            f32x4 s = (f32x4){0.f, 0.f, 0.f, 0.f};
            s = __builtin_amdgcn_mfma_f32_16x16x32_bf16(qa[0], kb0, s, 0, 0, 0);
            s = __builtin_amdgcn_mfma_f32_16x16x32_bf16(qa[1], kb1, s, 0, 0, 0);
            S[c] = s;
        }
#pragma unroll
        for (int c = 0; c < 2; ++c)
#pragma unroll
            for (int e = 0; e < 4; ++e) {
                int j = kt + 16 * c + r;
                int i = qw + quad * 4 + e;
                bool valid = (unsigned)(j - i + (WINDOW - 1)) <= (unsigned)(2 * WINDOW - 2);
                S[c][e] = valid ? S[c][e] : -1e30f;
            }
        float alpha[4], mnew[4];
#pragma unroll
        for (int e = 0; e < 4; ++e) {
            float v = fmaxf(S[0][e], S[1][e]);
#pragma unroll
            for (int off = 1; off <= 8; off <<= 1) v = fmaxf(v, __shfl_xor(v, off, 64));
            mnew[e] = fmaxf(m_run[e], v);
            alpha[e] = __expf(m_run[e] - mnew[e]);
            m_run[e] = mnew[e];
        }
#pragma unroll
        for (int c = 0; c < 2; ++c)
#pragma unroll
            for (int e = 0; e < 4; ++e) {
                float p = __expf(S[c][e] - mnew[e]);
                p = (S[c][e] <= -1e29f) ? 0.f : p;
                P[(quad * 4 + e) * 40 + 16 * c + r] = (__bf16)p;
            }
        bf16x8 pa = *(const bf16x8*)(P + r * 40 + quad * 8);
#pragma unroll
        for (int d = 0; d < 4; ++d)
#pragma unroll
            for (int e = 0; e < 4; ++e) acc[d][e] *= alpha[e];
        f32x4 ls = (f32x4){0.f, 0.f, 0.f, 0.f};
        ls = __builtin_amdgcn_mfma_f32_16x16x32_bf16(pa, ones, ls, 0, 0, 0);
#pragma unroll
        for (int e = 0; e < 4; ++e) l_run[e] = l_run[e] * alpha[e] + ls[e];
#pragma unroll
        for (int d = 0; d < 4; ++d) {
            const bf16* vrow = Vt + (size_t)(h * 64 + 16 * d + r) * SEQ + kt + quad * 8;
            bf16x8 vb = *(const bf16x8*)(vrow);
            acc[d] = __builtin_amdgcn_mfma_f32_16x16x32_bf16(pa, vb, acc[d], 0, 0, 0);
        }
    }

#pragma unroll
    for (int d = 0; d < 4; ++d)
#pragma unroll
        for (int e = 0; e < 4; ++e) {
            int i = qw + quad * 4 + e;
            o[(size_t)i * DMODEL + h * 64 + 16 * d + r] = (bf16)(acc[d][e] / l_run[e]);
        }
}

// ---------------- residual + layernorm, delta = f32 acc + f32 bias ----------------
__global__ __launch_bounds__(256)
void ln_residual_f32(bf16* __restrict__ x, const float* __restrict__ accd,
                     const float* __restrict__ bias,
                     const float* __restrict__ gamma, const float* __restrict__ beta)
{
    const int s = blockIdx.x, tid = threadIdx.x;
    const int lane = tid & 63, wave = tid >> 6;
    __shared__ float red[8];
    float v[4];
    float sum = 0.f;
#pragma unroll
    for (int i = 0; i < 4; ++i) {
        int d = i * 256 + tid;
        v[i] = (float)x[(size_t)s * 1024 + d] + accd[(size_t)s * 1024 + d] + bias[d];
        sum += v[i];
    }
#pragma unroll
    for (int off = 32; off; off >>= 1) sum += __shfl_xor(sum, off, 64);
    if (lane == 0) red[wave] = sum;
    __syncthreads();
    float mu = (red[0] + red[1] + red[2] + red[3]) * (1.f / 1024.f);
    float sq = 0.f;
#pragma unroll
    for (int i = 0; i < 4; ++i) { float t = v[i] - mu; sq += t * t; }
#pragma unroll
    for (int off = 32; off; off >>= 1) sq += __shfl_xor(sq, off, 64);
    if (lane == 0) red[wave + 4] = sq;
    __syncthreads();
    float var = (red[4] + red[5] + red[6] + red[7]) * (1.f / 1024.f);
    float inv = rsqrtf(var + LN_EPS);
#pragma unroll
    for (int i = 0; i < 4; ++i) {
        int d = i * 256 + tid;
        x[(size_t)s * 1024 + d] = (bf16)((v[i] - mu) * inv * gamma[d] + beta[d]);
    }
}

// ---------------- decoder: logits + log_softmax ----------------
__global__ __launch_bounds__(256)
void decoder(const bf16* __restrict__ x, const float* __restrict__ Wdec,
             const float* __restrict__ bdec, float* __restrict__ out)
{
    const int s = blockIdx.x * 4 + (threadIdx.x >> 6);
    const int lane = threadIdx.x & 63;
    float a0 = 0.f, a1 = 0.f, a2 = 0.f;
    for (int d = lane; d < 1024; d += 64) {
        float xv = (float)x[(size_t)s * 1024 + d];
        a0 += xv * Wdec[d];
        a1 += xv * Wdec[1024 + d];
        a2 += xv * Wdec[2048 + d];
    }
#pragma unroll
    for (int off = 32; off; off >>= 1) {
        a0 += __shfl_xor(a0, off, 64);
        a1 += __shfl_xor(a1, off, 64);
        a2 += __shfl_xor(a2, off, 64);
    }
    if (lane == 0) {
        float z0 = a0 + bdec[0];
        float z1 = a1 + bdec[1];
        float z2 = a2 + bdec[2];
        float mx = fmaxf(z0, fmaxf(z1, z2));
        float lse = mx + logf(__expf(z0 - mx) + __expf(z1 - mx) + __expf(z2 - mx));
        out[s * 3 + 0] = z0 - lse;
        out[s * 3 + 1] = z1 - lse;
        out[s * 3 + 2] = z2 - lse;
    }
}

extern "C" void kernel_launch(void* const* d_in, const int* in_sizes, int n_in,
                              void* d_out, int out_size, void* d_ws, size_t ws_size,
                              hipStream_t stream)
{
    const float* X    = (const float*)d_in[0];
    const float* Wqkv = (const float*)d_in[1];
    const float* bqkv = (const float*)d_in[2];
    const float* Wo   = (const float*)d_in[3];
    const float* bo   = (const float*)d_in[4];
    const float* ln1g = (const float*)d_in[5];
    const float* ln1b = (const float*)d_in[6];
    const float* W1   = (const float*)d_in[7];
    const float* b1   = (const float*)d_in[8];
    const float* W2   = (const float*)d_in[9];
    const float* b2   = (const float*)d_in[10];
    const float* ln2g = (const float*)d_in[11];
    const float* ln2b = (const float*)d_in[12];
    const float* Wdec = (const float*)d_in[13];
    const float* bdec = (const float*)d_in[14];

    // workspace (bf16 elems): x[2M] | buf[8M]=qkv6M/ao2M (reused as h) | tmp[2M]=Vt
    //                         accf: 2M f32 split-K accumulator
    bf16* ws   = (bf16*)d_ws;
    bf16* x    = ws;                                  // 2M
    bf16* buf  = x   + (size_t)SEQ * DMODEL;          // 8M
    bf16* qkv  = buf;
    bf16* ao   = buf + (size_t)SEQ * 3 * DMODEL;
    bf16* h    = buf;
    bf16* tmp  = buf + (size_t)SEQ * DFF;             // 2M (Vt)
    bf16* Vt   = tmp;
    float* accf = (float*)(tmp + (size_t)SEQ * DMODEL);   // 2M f32 (8 MB)

    add_pe<<<(SEQ * DMODEL) / 256, 256, 0, stream>>>(X, x);

    for (int l = 0; l < 4; ++l) {
        // QKV projection (direct, fused f32-W conversion)
        gemm_bt<0><<<dim3(3072 / 128, SEQ / 128), 256, 0, stream>>>(
            x, Wqkv + (size_t)l * 3072 * 1024, bqkv + l * 3072, qkv, SEQ, 3072, 1024);
        // banded flash attention
        transpose_v<<<dim3(SEQ / 64, DMODEL / 64), 256, 0, stream>>>(qkv, Vt);
        attn_mfma<<<(SEQ / 64) * NHEAD, 256, 0, stream>>>(qkv, Vt, ao);
        // O projection (split-K=4, f32 atomic; bias folded into LN)
        zero_f32<<<(SEQ * DMODEL / 4) / 256, 256, 0, stream>>>((float4*)accf);
        gemm_bt_splitk<4><<<dim3(1024 / 128, SEQ / 128, 4), 256, 0, stream>>>(
            ao, Wo + (size_t)l * 1024 * 1024, accf, SEQ, 1024, 1024);
        ln_residual_f32<<<SEQ, 256, 0, stream>>>(x, accf, bo + l * 1024,
                                                 ln1g + l * 1024, ln1b + l * 1024);
        // FF1 (relu, direct) — h overwrites qkv/ao region
        gemm_bt<1><<<dim3(4096 / 128, SEQ / 128), 256, 0, stream>>>(
            x, W1 + (size_t)l * 4096 * 1024, b1 + l * 4096, h, SEQ, 4096, 1024);
        // FF2 (split-K=4, f32 atomic; bias folded into LN)
        zero_f32<<<(SEQ * DMODEL / 4) / 256, 256, 0, stream>>>((float4*)accf);
        gemm_bt_splitk<4><<<dim3(1024 / 128, SEQ / 128, 4), 256, 0, stream>>>(
            h, W2 + (size_t)l * 1024 * 4096, accf, SEQ, 1024, 4096);
        ln_residual_f32<<<SEQ, 256, 0, stream>>>(x, accf, b2 + l * 1024,
                                                 ln2g + l * 1024, ln2b + l * 1024);
    }

    decoder<<<SEQ / 4, 256, 0, stream>>>(x, Wdec, bdec, (float*)d_out);
}